// Round 2
// baseline (663.822 us; speedup 1.0000x reference)
//
#include <hip/hip_runtime.h>

typedef __bf16 bf16_t;
typedef __attribute__((ext_vector_type(8))) __bf16 bf16x8;
typedef __attribute__((ext_vector_type(4))) float f32x4;

static constexpr int Lc = 2, NEc = 4, Hc = 768, FFc = 3072, NHc = 12;
static constexpr int Bc = 8, Tc = 2048;

__device__ __forceinline__ void gll16(const bf16_t* g, bf16_t* l) {
  __builtin_amdgcn_global_load_lds(
      (const __attribute__((address_space(1))) void*)g,
      (__attribute__((address_space(3))) void*)l, 16, 0, 0);
}

// ---------------------------------------------------------------- prep: block 0 = route (wave 0), blocks 1.. = PE add
__global__ __launch_bounds__(256) void prep_k(const float* __restrict__ xin,
                                              const int* __restrict__ ntp,
                                              float* __restrict__ x0,
                                              int* __restrict__ perm,
                                              int* __restrict__ offs) {
  if (blockIdx.x == 0) {
    int tid = threadIdx.x;
    if (tid >= 64) return;
    int lane = tid;
    int myE[32];
    int cnt0 = 0, cnt1 = 0, cnt2 = 0, cnt3 = 0;
    for (int c = 0; c < 32; ++c) {
      int e = ntp[c * 64 + lane];
      myE[c] = e;
      cnt0 += __popcll(__ballot(e == 0));
      cnt1 += __popcll(__ballot(e == 1));
      cnt2 += __popcll(__ballot(e == 2));
      cnt3 += __popcll(__ballot(e == 3));
    }
    int b0 = 0, b1 = cnt0, b2 = cnt0 + cnt1, b3 = cnt0 + cnt1 + cnt2;
    if (lane == 0) {
      offs[0] = 0; offs[1] = b1; offs[2] = b2; offs[3] = b3; offs[4] = b3 + cnt3;
    }
    unsigned long long below = (lane == 63) ? ~0ull >> 1 : ((1ull << lane) - 1);
    for (int c = 0; c < 32; ++c) {
      int e = myE[c];
      unsigned long long m0 = __ballot(e == 0), m1 = __ballot(e == 1);
      unsigned long long m2 = __ballot(e == 2), m3 = __ballot(e == 3);
      unsigned long long mm = (e == 0) ? m0 : (e == 1) ? m1 : (e == 2) ? m2 : m3;
      int base = (e == 0) ? b0 : (e == 1) ? b1 : (e == 2) ? b2 : b3;
      perm[base + __popcll(mm & below)] = c * 64 + lane;
      b0 += __popcll(m0); b1 += __popcll(m1); b2 += __popcll(m2); b3 += __popcll(m3);
    }
    return;
  }
  int p = (blockIdx.x - 1) * 256 + threadIdx.x;  // pair index over T*H/2
  int t = p / 384;
  int jj = p - t * 384;
  int s = t & 255;
  float ang = (float)s * __expf((float)jj * -0.0239852613894f);
  float sn, cs;
  sincosf(ang, &sn, &cs);
  float2 xv = ((const float2*)xin)[p];
  float2 o;  o.x = xv.x + sn;  o.y = xv.y + cs;
  ((float2*)x0)[p] = o;
}

// ---------------------------------------------------------------- LayerNorm
__global__ __launch_bounds__(256) void ln_k(const float* __restrict__ x,
                                            const float* __restrict__ g,
                                            const float* __restrict__ bb,
                                            bf16_t* __restrict__ out) {
  int w = threadIdx.x >> 6, lane = threadIdx.x & 63;
  int t = blockIdx.x * 4 + w;
  const float4* xr = (const float4*)(x + (size_t)t * Hc);
  float4 v[3];
  float s = 0.f, s2 = 0.f;
  for (int i = 0; i < 3; ++i) {
    v[i] = xr[lane + i * 64];
    s  += v[i].x + v[i].y + v[i].z + v[i].w;
    s2 += v[i].x * v[i].x + v[i].y * v[i].y + v[i].z * v[i].z + v[i].w * v[i].w;
  }
  for (int o = 1; o < 64; o <<= 1) { s += __shfl_xor(s, o); s2 += __shfl_xor(s2, o); }
  float mu = s * (1.f / 768.f);
  float r = rsqrtf(s2 * (1.f / 768.f) - mu * mu + 1e-5f);
  bf16_t* orow = out + (size_t)t * Hc;
  for (int i = 0; i < 3; ++i) {
    int i4 = lane + i * 64;
    float4 gg = ((const float4*)g)[i4];
    float4 b4 = ((const float4*)bb)[i4];
    union { bf16_t h[4]; uint2 u; } pk;
    pk.h[0] = (bf16_t)((v[i].x - mu) * r * gg.x + b4.x);
    pk.h[1] = (bf16_t)((v[i].y - mu) * r * gg.y + b4.y);
    pk.h[2] = (bf16_t)((v[i].z - mu) * r * gg.z + b4.z);
    pk.h[3] = (bf16_t)((v[i].w - mu) * r * gg.w + b4.w);
    ((uint2*)orow)[i4] = pk.u;
  }
}

// ---------------------------------------------------------------- unified transpose+convert fp32 [K,N] -> bf16 [N,K]
__global__ __launch_bounds__(256) void tconv_all(const float* __restrict__ Wq,
                                                 const float* __restrict__ Wk,
                                                 const float* __restrict__ Wv,
                                                 const float* __restrict__ W1,
                                                 const float* __restrict__ W2,
                                                 bf16_t* __restrict__ wqkvt,
                                                 bf16_t* __restrict__ w1t,
                                                 bf16_t* __restrict__ w2t) {
  int t = blockIdx.x;
  const float* src;
  bf16_t* d;
  int K, N, n0, k0;
  if (t < 864) {
    int z = t / 144, r = t % 144;
    int l = z / 3, m = z % 3;
    src = (m == 0 ? Wq : (m == 1 ? Wk : Wv)) + (size_t)l * Hc * Hc;
    d = wqkvt + (size_t)l * 2304 * 768 + (size_t)m * Hc * Hc;
    K = 768; N = 768;
    n0 = (r % 12) * 64; k0 = (r / 12) * 64;
  } else if (t < 864 + 4608) {
    t -= 864;
    int z = t / 576, r = t % 576;
    src = W1 + (size_t)z * Hc * FFc;
    d = w1t + (size_t)z * FFc * Hc;
    K = 768; N = 3072;
    n0 = (r % 48) * 64; k0 = (r / 48) * 64;
  } else {
    t -= 864 + 4608;
    int z = t / 576, r = t % 576;
    src = W2 + (size_t)z * FFc * Hc;
    d = w2t + (size_t)z * Hc * FFc;
    K = 3072; N = 768;
    n0 = (r % 12) * 64; k0 = (r / 12) * 64;
  }
  __shared__ float tl[64][65];
  // read side: lane = r0*16 + c4 ; float4 per lane
  int c4 = threadIdx.x & 15, r0 = threadIdx.x >> 4;
  for (int i = 0; i < 4; ++i) {
    int r = r0 + i * 16;
    float4 v = *(const float4*)(src + (size_t)(k0 + r) * N + n0 + c4 * 4);
    tl[r][c4 * 4 + 0] = v.x;
    tl[r][c4 * 4 + 1] = v.y;
    tl[r][c4 * 4 + 2] = v.z;
    tl[r][c4 * 4 + 3] = v.w;
  }
  __syncthreads();
  // write side: lane = rr0*8 + c8 ; 8 bf16 (16B) per lane, k-contiguous
  int c8 = threadIdx.x & 7, rr0 = threadIdx.x >> 3;
  for (int i = 0; i < 2; ++i) {
    int rr = rr0 + i * 32;
    union { bf16_t h[8]; uint4 u; } pk;
    for (int j = 0; j < 8; ++j) pk.h[j] = (bf16_t)tl[c8 * 8 + j][rr];
    *(uint4*)(d + (size_t)(n0 + rr) * K + k0 + c8 * 8) = pk.u;
  }
}

// ---------------------------------------------------------------- GEMM, BM=128, BN=128, BK=64, 4 waves (2x2, 64x64 each)
// m97 structure scaled up: LDS rows of 64 bf16 (8 chunks of 8), rotation swizzle:
// slot s of row r holds global chunk (s-r)&7. gll16 width-16 staging, linear LDS.
// MODE 0: QKV (out bf16 + range bias)  MODE 1: FFN1 (gather via perm, GELU, grouped out)
// MODE 2: FFN2 split-K=2 -> fp32 partial buffers
template <int MODE>
__global__ __launch_bounds__(256) void gemm3(
    const bf16_t* __restrict__ A, const bf16_t* __restrict__ Bt,
    int K, int N, int kIters, long btStride, long biasStride,
    const int* __restrict__ perm, const int* __restrict__ offs,
    const float* __restrict__ bqp, const float* __restrict__ bkp,
    const float* __restrict__ bvp, const float* __restrict__ biasE,
    float* __restrict__ outF, bf16_t* __restrict__ outB) {
  __shared__ bf16_t Ald[128 * 64];
  __shared__ bf16_t Bld[128 * 64];
  int tid = threadIdx.x, lane = tid & 63, w = tid >> 6;
  int quad = lane >> 4, col = lane & 15;
  int m0 = blockIdx.y * 128, n0 = blockIdx.x * 128;
  int e = 0, ks = 0, kStart = 0, off = 0, cnt = Tc;
  if (MODE == 1) e = blockIdx.z;
  if (MODE == 2) { e = blockIdx.z >> 1; ks = blockIdx.z & 1; kStart = ks * (K / 2); }
  if (MODE != 0) {
    off = offs[e];
    cnt = offs[e + 1] - off;
    if (m0 >= cnt) return;
  }
  const bf16_t* B0 = Bt + (size_t)e * btStride;

  // A staging: wave w covers rows [w*32, w*32+32), 4 gll16 (8 rows each)
  const bf16_t* ga[4];
  bf16_t* la[4];
  for (int j = 0; j < 4; ++j) {
    int rbase = w * 32 + j * 8;
    int row = rbase + (lane >> 3);
    int ch = ((lane & 7) - row) & 7;
    int gm = m0 + row;
    int gmc = (gm < cnt) ? gm : (cnt - 1);
    int srow;
    if (MODE == 0) srow = gm;
    else if (MODE == 1) srow = perm[off + gmc];
    else srow = off + gmc;
    ga[j] = A + (size_t)srow * K + kStart + ch * 8;
    la[j] = Ald + rbase * 64;
  }
  // B staging: same shape
  const bf16_t* gb[4];
  bf16_t* lb[4];
  for (int j = 0; j < 4; ++j) {
    int rbase = w * 32 + j * 8;
    int row = rbase + (lane >> 3);
    int ch = ((lane & 7) - row) & 7;
    gb[j] = B0 + (size_t)(n0 + row) * K + kStart + ch * 8;
    lb[j] = Bld + rbase * 64;
  }

  int wr = (w >> 1) * 64, wc = (w & 1) * 64;
  int aoff[4], boff[4];
  for (int r = 0; r < 4; ++r) {
    int row = wr + r * 16 + col;
    aoff[r] = row * 64 + (((quad + row) & 7) << 3);
  }
  for (int c = 0; c < 4; ++c) {
    int row = wc + c * 16 + col;
    boff[c] = row * 64 + (((quad + row) & 7) << 3);
  }

  const f32x4 z4 = {0.f, 0.f, 0.f, 0.f};
  f32x4 acc[4][4];
  for (int r = 0; r < 4; ++r)
    for (int c = 0; c < 4; ++c) acc[r][c] = z4;

  for (int it = 0; it < kIters; ++it) {
    __syncthreads();
    for (int j = 0; j < 4; ++j) { gll16(ga[j], la[j]); ga[j] += 64; }
    for (int j = 0; j < 4; ++j) { gll16(gb[j], lb[j]); gb[j] += 64; }
    __syncthreads();
    for (int kk = 0; kk < 2; ++kk) {
      bf16x8 af[4], bv[4];
      for (int r = 0; r < 4; ++r) af[r] = *(const bf16x8*)(Ald + (aoff[r] ^ (kk << 5)));
      for (int c = 0; c < 4; ++c) bv[c] = *(const bf16x8*)(Bld + (boff[c] ^ (kk << 5)));
      for (int r = 0; r < 4; ++r)
        for (int c = 0; c < 4; ++c)
          acc[r][c] = __builtin_amdgcn_mfma_f32_16x16x32_bf16(af[r], bv[c], acc[r][c], 0, 0, 0);
    }
  }

  for (int r = 0; r < 4; ++r)
    for (int c = 0; c < 4; ++c) {
      int mloc = wr + r * 16 + quad * 4;
      int n = n0 + wc + c * 16 + col;
      for (int i = 0; i < 4; ++i) {
        int gm = m0 + mloc + i;
        float av = acc[r][c][i];
        if (MODE == 0) {
          float bias = (n < 768) ? bqp[n] : (n < 1536) ? bkp[n - 768] : bvp[n - 1536];
          outB[(size_t)gm * N + n] = (bf16_t)(av + bias);
        } else if (MODE == 1) {
          if (gm < cnt) {
            float v = av + biasE[(size_t)e * biasStride + n];
            float u = v * (0.7978845608f + 0.0356774081f * v * v);
            float t = 1.f - 2.f / (1.f + __expf(2.f * u));
            outB[(size_t)(off + gm) * N + n] = (bf16_t)(0.5f * v * (1.f + t));
          }
        } else {
          if (gm < cnt) {
            int tok = perm[off + gm];
            outF[(size_t)ks * Tc * Hc + (size_t)tok * N + n] = av;
          }
        }
      }
    }
}

// ---------------------------------------------------------------- attention
__global__ __launch_bounds__(256) void attn_k(const bf16_t* __restrict__ qkv,
                                              const int* __restrict__ np,
                                              float* __restrict__ x) {
  __shared__ bf16_t Kld[256 * 64];  // reused as P after scores
  __shared__ bf16_t Vt[64 * 256];   // V transposed [d][s], swizzled
  int tid = threadIdx.x, lane = tid & 63, w = tid >> 6;
  int qt = blockIdx.x;
  int b = blockIdx.y / NHc, h = blockIdx.y % NHc;

  for (int j = 0; j < 8; ++j) {
    int rbase = w * 64 + j * 8;
    int row = rbase + (lane >> 3);
    int oc = ((lane & 7) - row) & 7;
    const bf16_t* gp = qkv + ((size_t)(b * 256 + row)) * 2304 + 768 + h * 64 + oc * 8;
    gll16(gp, Kld + rbase * 64);
  }
  {
    int s = tid, shi = s >> 3, slo = s & 7;
    const uint4* vs = (const uint4*)(qkv + ((size_t)(b * 256 + s)) * 2304 + 1536 + h * 64);
    for (int cc = 0; cc < 8; ++cc) {
      uint4 pk = vs[cc];
      const bf16_t* pv = (const bf16_t*)&pk;
      for (int jj = 0; jj < 8; ++jj) {
        int d = cc * 8 + jj;
        Vt[d * 256 + ((shi + d) & 31) * 8 + slo] = pv[jj];
      }
    }
  }
  int quad = lane >> 4, col = lane & 15;
  float madd[16];
  for (int nt = 0; nt < 16; ++nt)
    madd[nt] = (np[b * 256 + nt * 16 + col] != 0) ? 0.f : -10000.f;
  int qrow = qt * 64 + w * 16 + col;
  const bf16_t* qb = qkv + ((size_t)(b * 256 + qrow)) * 2304 + h * 64;
  bf16x8 qf0 = *(const bf16x8*)(qb + quad * 8);
  bf16x8 qf1 = *(const bf16x8*)(qb + 32 + quad * 8);
  __syncthreads();

  const f32x4 z4 = {0.f, 0.f, 0.f, 0.f};
  f32x4 sc[16];
  for (int nt = 0; nt < 16; ++nt) {
    int row = nt * 16 + col;
    bf16x8 k0 = *(const bf16x8*)(Kld + row * 64 + (((0 + quad + row) & 7) << 3));
    bf16x8 k1 = *(const bf16x8*)(Kld + row * 64 + (((4 + quad + row) & 7) << 3));
    f32x4 z = z4;
    z = __builtin_amdgcn_mfma_f32_16x16x32_bf16(qf0, k0, z, 0, 0, 0);
    z = __builtin_amdgcn_mfma_f32_16x16x32_bf16(qf1, k1, z, 0, 0, 0);
    sc[nt] = z;
  }
  for (int nt = 0; nt < 16; ++nt) {
    float a = madd[nt];
    sc[nt][0] += a; sc[nt][1] += a; sc[nt][2] += a; sc[nt][3] += a;
  }
  float pm[4], rl[4];
  for (int i = 0; i < 4; ++i) {
    float m = -1e30f;
    for (int nt = 0; nt < 16; ++nt) m = fmaxf(m, sc[nt][i]);
    for (int o = 1; o < 16; o <<= 1) m = fmaxf(m, __shfl_xor(m, o));
    float ssum = 0.f;
    for (int nt = 0; nt < 16; ++nt) ssum += __expf(sc[nt][i] - m);
    for (int o = 1; o < 16; o <<= 1) ssum += __shfl_xor(ssum, o);
    pm[i] = m;
    rl[i] = 1.f / ssum;
  }
  __syncthreads();
  bf16_t* Pb = Kld + w * 4096;
  for (int nt = 0; nt < 16; ++nt)
    for (int i = 0; i < 4; ++i) {
      int prow = quad * 4 + i;
      int key = nt * 16 + col;
      Pb[prow * 256 + (((key >> 3) + prow) & 31) * 8 + (key & 7)] =
          (bf16_t)__expf(sc[nt][i] - pm[i]);
    }
  __syncthreads();
  f32x4 oacc[4];
  for (int i = 0; i < 4; ++i) oacc[i] = z4;
  for (int kk2 = 0; kk2 < 8; ++kk2) {
    bf16x8 pa = *(const bf16x8*)(Pb + col * 256 + (((kk2 * 4 + quad + col) & 31) << 3));
    for (int nt2 = 0; nt2 < 4; ++nt2) {
      int d = nt2 * 16 + col;
      bf16x8 bv8 = *(const bf16x8*)(Vt + d * 256 + (((kk2 * 4 + quad + d) & 31) << 3));
      oacc[nt2] = __builtin_amdgcn_mfma_f32_16x16x32_bf16(pa, bv8, oacc[nt2], 0, 0, 0);
    }
  }
  for (int nt2 = 0; nt2 < 4; ++nt2)
    for (int i = 0; i < 4; ++i) {
      size_t o = ((size_t)(b * 256 + qt * 64 + w * 16 + quad * 4 + i)) * Hc + h * 64 + nt2 * 16 + col;
      x[o] += oacc[nt2][i] * rl[i];
    }
}

// ---------------------------------------------------------------- combine partials + residual + b2 + permute
__global__ __launch_bounds__(256) void combine_k(const float* __restrict__ x0,
                                                 const float* __restrict__ pbuf,
                                                 const float* __restrict__ b2l,
                                                 const int* __restrict__ ntp,
                                                 const int* __restrict__ np,
                                                 float* __restrict__ dst) {
  int i = blockIdx.x * 256 + threadIdx.x;  // float4 index over 2048*192
  int t = i / 192, d = i - t * 192;
  int idx = np[t];
  float4 o;
  if (idx != 0) {
    int r = idx - 1;
    int e = ntp[r];
    size_t j = (size_t)r * 192 + d;
    float4 a = ((const float4*)x0)[j];
    float4 p0 = ((const float4*)pbuf)[j];
    float4 p1 = ((const float4*)pbuf)[(size_t)Tc * 192 + j];
    float4 bb = ((const float4*)(b2l + (size_t)e * Hc))[d];
    o.x = a.x + p0.x + p1.x + bb.x;
    o.y = a.y + p0.y + p1.y + bb.y;
    o.z = a.z + p0.z + p1.z + bb.z;
    o.w = a.w + p0.w + p1.w + bb.w;
  } else {
    o.x = o.y = o.z = o.w = 0.f;
  }
  ((float4*)dst)[i] = o;
}

// ---------------------------------------------------------------- host
extern "C" void kernel_launch(void* const* d_in, const int* in_sizes, int n_in,
                              void* d_out, int out_size, void* d_ws, size_t ws_size,
                              hipStream_t stream) {
  const float* x_in = (const float*)d_in[0];
  const int* note_pos = (const int*)d_in[1];
  const int* ntp = (const int*)d_in[2];
  const float* Wq = (const float*)d_in[3];
  const float* bq = (const float*)d_in[4];
  const float* Wk = (const float*)d_in[5];
  const float* bk = (const float*)d_in[6];
  const float* Wv = (const float*)d_in[7];
  const float* bv = (const float*)d_in[8];
  const float* ln1w = (const float*)d_in[9];
  const float* ln1b = (const float*)d_in[10];
  const float* ln2w = (const float*)d_in[11];
  const float* ln2b = (const float*)d_in[12];
  const float* W1 = (const float*)d_in[13];
  const float* b1 = (const float*)d_in[14];
  const float* W2 = (const float*)d_in[15];
  const float* b2 = (const float*)d_in[16];
  float* out = (float*)d_out;

  char* p = (char*)d_ws;
  auto carve = [&](size_t bytes) -> char* {
    char* r = p;
    p += (bytes + 255) & ~(size_t)255;
    return r;
  };
  float* xA = (float*)carve((size_t)Tc * Hc * 4);
  float* xB = (float*)carve((size_t)Tc * Hc * 4);
  float* pbuf = (float*)carve((size_t)2 * Tc * Hc * 4);
  bf16_t* h16 = (bf16_t*)carve((size_t)Tc * Hc * 2);
  bf16_t* big = (bf16_t*)carve((size_t)Tc * FFc * 2);  // union: qkv16 / act1
  bf16_t* qkv16 = big;
  bf16_t* act1 = big;
  bf16_t* wqkvt = (bf16_t*)carve((size_t)Lc * 2304 * 768 * 2);
  bf16_t* w1t = (bf16_t*)carve((size_t)Lc * NEc * FFc * Hc * 2);
  bf16_t* w2t = (bf16_t*)carve((size_t)Lc * NEc * Hc * FFc * 2);
  int* perm = (int*)carve(Tc * 4);
  int* offs = (int*)carve(64);

  prep_k<<<1 + Tc * Hc / 2 / 256, 256, 0, stream>>>(x_in, ntp, xA, perm, offs);
  tconv_all<<<864 + 4608 + 4608, 256, 0, stream>>>(Wq, Wk, Wv, W1, W2, wqkvt, w1t, w2t);

  float* xcur = xA;
  for (int l = 0; l < Lc; ++l) {
    float* xdst = (l == Lc - 1) ? out : xB;
    ln_k<<<Tc / 4, 256, 0, stream>>>(xcur, ln1w + l * Hc, ln1b + l * Hc, h16);
    gemm3<0><<<dim3(18, 16, 1), 256, 0, stream>>>(
        h16, wqkvt + (size_t)l * 2304 * 768, Hc, 2304, 12, 0L, 0L, perm, offs,
        bq + l * Hc, bk + l * Hc, bv + l * Hc, nullptr, nullptr, qkv16);
    attn_k<<<dim3(4, Bc * NHc), 256, 0, stream>>>(qkv16, note_pos, xcur);
    ln_k<<<Tc / 4, 256, 0, stream>>>(xcur, ln2w + l * Hc, ln2b + l * Hc, h16);
    gemm3<1><<<dim3(24, 16, NEc), 256, 0, stream>>>(
        h16, w1t + (size_t)l * NEc * FFc * Hc, Hc, FFc, 12, (long)FFc * Hc, (long)FFc,
        perm, offs, nullptr, nullptr, nullptr, b1 + (size_t)l * NEc * FFc, nullptr, act1);
    gemm3<2><<<dim3(6, 16, NEc * 2), 256, 0, stream>>>(
        act1, w2t + (size_t)l * NEc * Hc * FFc, FFc, Hc, 24, (long)Hc * FFc, 0L,
        perm, offs, nullptr, nullptr, nullptr, nullptr, pbuf, nullptr);
    combine_k<<<Tc * 192 / 256, 256, 0, stream>>>(xcur, pbuf, b2 + (size_t)l * NEc * Hc,
                                                  ntp, note_pos, xdst);
    float* tmp = xcur; xcur = xdst; xB = tmp;  // ping-pong
  }
}

// Round 7
// 429.345 us; speedup vs baseline: 1.5461x; 1.5461x over previous
//
#include <hip/hip_runtime.h>

typedef __bf16 bf16_t;
typedef __attribute__((ext_vector_type(8))) __bf16 bf16x8;
typedef __attribute__((ext_vector_type(4))) float f32x4;

static constexpr int Lc = 2, NEc = 4, Hc = 768, FFc = 3072, NHc = 12;
static constexpr int Bc = 8, Tc = 2048;

__device__ __forceinline__ void gll16(const bf16_t* g, bf16_t* l) {
  __builtin_amdgcn_global_load_lds(
      (const __attribute__((address_space(1))) void*)g,
      (__attribute__((address_space(3))) void*)l, 16, 0, 0);
}

// ---------------------------------------------------------------- prep: block 0 = route (wave 0), blocks 1.. = PE add
__global__ __launch_bounds__(256) void prep_k(const float* __restrict__ xin,
                                              const int* __restrict__ ntp,
                                              float* __restrict__ x0,
                                              int* __restrict__ perm,
                                              int* __restrict__ offs) {
  if (blockIdx.x == 0) {
    int tid = threadIdx.x;
    if (tid >= 64) return;
    int lane = tid;
    int myE[32];
    int cnt0 = 0, cnt1 = 0, cnt2 = 0, cnt3 = 0;
    for (int c = 0; c < 32; ++c) {
      int e = ntp[c * 64 + lane];
      myE[c] = e;
      cnt0 += __popcll(__ballot(e == 0));
      cnt1 += __popcll(__ballot(e == 1));
      cnt2 += __popcll(__ballot(e == 2));
      cnt3 += __popcll(__ballot(e == 3));
    }
    int b0 = 0, b1 = cnt0, b2 = cnt0 + cnt1, b3 = cnt0 + cnt1 + cnt2;
    if (lane == 0) {
      offs[0] = 0; offs[1] = b1; offs[2] = b2; offs[3] = b3; offs[4] = b3 + cnt3;
    }
    unsigned long long below = (lane == 63) ? ~0ull >> 1 : ((1ull << lane) - 1);
    for (int c = 0; c < 32; ++c) {
      int e = myE[c];
      unsigned long long m0 = __ballot(e == 0), m1 = __ballot(e == 1);
      unsigned long long m2 = __ballot(e == 2), m3 = __ballot(e == 3);
      unsigned long long mm = (e == 0) ? m0 : (e == 1) ? m1 : (e == 2) ? m2 : m3;
      int base = (e == 0) ? b0 : (e == 1) ? b1 : (e == 2) ? b2 : b3;
      perm[base + __popcll(mm & below)] = c * 64 + lane;
      b0 += __popcll(m0); b1 += __popcll(m1); b2 += __popcll(m2); b3 += __popcll(m3);
    }
    return;
  }
  int p = (blockIdx.x - 1) * 256 + threadIdx.x;  // pair index over T*H/2
  int t = p / 384;
  int jj = p - t * 384;
  int s = t & 255;
  float ang = (float)s * __expf((float)jj * -0.0239852613894f);
  float sn, cs;
  sincosf(ang, &sn, &cs);
  float2 xv = ((const float2*)xin)[p];
  float2 o;  o.x = xv.x + sn;  o.y = xv.y + cs;
  ((float2*)x0)[p] = o;
}

// ---------------------------------------------------------------- LayerNorm
__global__ __launch_bounds__(256) void ln_k(const float* __restrict__ x,
                                            const float* __restrict__ g,
                                            const float* __restrict__ bb,
                                            bf16_t* __restrict__ out) {
  int w = threadIdx.x >> 6, lane = threadIdx.x & 63;
  int t = blockIdx.x * 4 + w;
  const float4* xr = (const float4*)(x + (size_t)t * Hc);
  float4 v[3];
  float s = 0.f, s2 = 0.f;
  for (int i = 0; i < 3; ++i) {
    v[i] = xr[lane + i * 64];
    s  += v[i].x + v[i].y + v[i].z + v[i].w;
    s2 += v[i].x * v[i].x + v[i].y * v[i].y + v[i].z * v[i].z + v[i].w * v[i].w;
  }
  for (int o = 1; o < 64; o <<= 1) { s += __shfl_xor(s, o); s2 += __shfl_xor(s2, o); }
  float mu = s * (1.f / 768.f);
  float r = rsqrtf(s2 * (1.f / 768.f) - mu * mu + 1e-5f);
  bf16_t* orow = out + (size_t)t * Hc;
  for (int i = 0; i < 3; ++i) {
    int i4 = lane + i * 64;
    float4 gg = ((const float4*)g)[i4];
    float4 b4 = ((const float4*)bb)[i4];
    union { bf16_t h[4]; uint2 u; } pk;
    pk.h[0] = (bf16_t)((v[i].x - mu) * r * gg.x + b4.x);
    pk.h[1] = (bf16_t)((v[i].y - mu) * r * gg.y + b4.y);
    pk.h[2] = (bf16_t)((v[i].z - mu) * r * gg.z + b4.z);
    pk.h[3] = (bf16_t)((v[i].w - mu) * r * gg.w + b4.w);
    ((uint2*)orow)[i4] = pk.u;
  }
}

// ---------------------------------------------------------------- unified transpose+convert fp32 [K,N] -> bf16 [N,K]
__global__ __launch_bounds__(256) void tconv_all(const float* __restrict__ Wq,
                                                 const float* __restrict__ Wk,
                                                 const float* __restrict__ Wv,
                                                 const float* __restrict__ W1,
                                                 const float* __restrict__ W2,
                                                 bf16_t* __restrict__ wqkvt,
                                                 bf16_t* __restrict__ w1t,
                                                 bf16_t* __restrict__ w2t) {
  int t = blockIdx.x;
  const float* src;
  bf16_t* d;
  int K, N, n0, k0;
  if (t < 864) {
    int z = t / 144, r = t % 144;
    int l = z / 3, m = z % 3;
    src = (m == 0 ? Wq : (m == 1 ? Wk : Wv)) + (size_t)l * Hc * Hc;
    d = wqkvt + (size_t)l * 2304 * 768 + (size_t)m * Hc * Hc;
    K = 768; N = 768;
    n0 = (r % 12) * 64; k0 = (r / 12) * 64;
  } else if (t < 864 + 4608) {
    t -= 864;
    int z = t / 576, r = t % 576;
    src = W1 + (size_t)z * Hc * FFc;
    d = w1t + (size_t)z * FFc * Hc;
    K = 768; N = 3072;
    n0 = (r % 48) * 64; k0 = (r / 48) * 64;
  } else {
    t -= 864 + 4608;
    int z = t / 576, r = t % 576;
    src = W2 + (size_t)z * FFc * Hc;
    d = w2t + (size_t)z * Hc * FFc;
    K = 3072; N = 768;
    n0 = (r % 12) * 64; k0 = (r / 12) * 64;
  }
  __shared__ float tl[64][65];
  // read side: lane = r0*16 + c4 ; float4 per lane
  int c4 = threadIdx.x & 15, r0 = threadIdx.x >> 4;
  for (int i = 0; i < 4; ++i) {
    int r = r0 + i * 16;
    float4 v = *(const float4*)(src + (size_t)(k0 + r) * N + n0 + c4 * 4);
    tl[r][c4 * 4 + 0] = v.x;
    tl[r][c4 * 4 + 1] = v.y;
    tl[r][c4 * 4 + 2] = v.z;
    tl[r][c4 * 4 + 3] = v.w;
  }
  __syncthreads();
  // write side: lane = rr0*8 + c8 ; 8 bf16 (16B) per lane, k-contiguous
  int c8 = threadIdx.x & 7, rr0 = threadIdx.x >> 3;
  for (int i = 0; i < 2; ++i) {
    int rr = rr0 + i * 32;
    union { bf16_t h[8]; uint4 u; } pk;
    for (int j = 0; j < 8; ++j) pk.h[j] = (bf16_t)tl[c8 * 8 + j][rr];
    *(uint4*)(d + (size_t)(n0 + rr) * K + k0 + c8 * 8) = pk.u;
  }
}

// ---------------------------------------------------------------- GEMM, BM=128, BN=64, BK=64, 4 waves (2x2, each 64x32)
// LDS rows: 64 bf16 (8 chunks of 8), rotation swizzle: slot s of row r holds chunk (s-r)&7.
// Vectorized LDS-staged epilogue (full-line stores).
// MODE 0: QKV (bf16 out + range bias)  MODE 1: FFN1 (gather via perm, GELU, grouped out)
// MODE 2: FFN2 split-K=2 -> fp32 partial buffers (scatter by tok)
template <int MODE>
__global__ __launch_bounds__(256, 2) void gemm4(
    const bf16_t* __restrict__ A, const bf16_t* __restrict__ Bt,
    int K, int N, int kIters, long btStride, long biasStride,
    const int* __restrict__ perm, const int* __restrict__ offs,
    const float* __restrict__ bqp, const float* __restrict__ bkp,
    const float* __restrict__ bvp, const float* __restrict__ biasE,
    float* __restrict__ outF, bf16_t* __restrict__ outB) {
  __shared__ __align__(16) char smem[24576];
  bf16_t* Ald = (bf16_t*)smem;           // 128x64 = 16KB
  bf16_t* Bld = Ald + 128 * 64;          // 64x64  =  8KB
  int tid = threadIdx.x, lane = tid & 63, w = tid >> 6;
  int quad = lane >> 4, col = lane & 15;
  int m0 = blockIdx.y * 128, n0 = blockIdx.x * 64;
  int e = 0, ks = 0, kStart = 0, off = 0, cnt = Tc;
  if (MODE == 1) e = blockIdx.z;
  if (MODE == 2) { e = blockIdx.z >> 1; ks = blockIdx.z & 1; kStart = ks * (K / 2); }
  if (MODE != 0) {
    off = offs[e];
    cnt = offs[e + 1] - off;
    if (m0 >= cnt) return;
  }
  const bf16_t* B0 = Bt + (size_t)e * btStride;

  // A staging: wave w covers rows [w*32, w*32+32), 4 gll16 (8 rows each)
  const bf16_t* ga[4];
  bf16_t* la[4];
  for (int j = 0; j < 4; ++j) {
    int rbase = w * 32 + j * 8;
    int row = rbase + (lane >> 3);
    int ch = ((lane & 7) - row) & 7;
    int gm = m0 + row;
    int gmc = (gm < cnt) ? gm : (cnt - 1);
    int srow;
    if (MODE == 0) srow = gm;
    else if (MODE == 1) srow = perm[off + gmc];
    else srow = off + gmc;
    ga[j] = A + (size_t)srow * K + kStart + ch * 8;
    la[j] = Ald + rbase * 64;
  }
  // B staging: wave w covers rows [w*16, w*16+16), 2 gll16
  const bf16_t* gb[2];
  bf16_t* lb[2];
  for (int j = 0; j < 2; ++j) {
    int rbase = w * 16 + j * 8;
    int row = rbase + (lane >> 3);
    int ch = ((lane & 7) - row) & 7;
    gb[j] = B0 + (size_t)(n0 + row) * K + kStart + ch * 8;
    lb[j] = Bld + rbase * 64;
  }

  int wr = (w >> 1) * 64, wc = (w & 1) * 32;
  int aoff[4], boff[2];
  for (int r = 0; r < 4; ++r) {
    int row = wr + r * 16 + col;
    aoff[r] = row * 64 + (((quad + row) & 7) << 3);
  }
  for (int c = 0; c < 2; ++c) {
    int row = wc + c * 16 + col;
    boff[c] = row * 64 + (((quad + row) & 7) << 3);
  }

  const f32x4 z4 = {0.f, 0.f, 0.f, 0.f};
  f32x4 acc[4][2];
  for (int r = 0; r < 4; ++r)
    for (int c = 0; c < 2; ++c) acc[r][c] = z4;

  for (int it = 0; it < kIters; ++it) {
    __syncthreads();
    for (int j = 0; j < 4; ++j) { gll16(ga[j], la[j]); ga[j] += 64; }
    for (int j = 0; j < 2; ++j) { gll16(gb[j], lb[j]); gb[j] += 64; }
    __syncthreads();
    for (int kk = 0; kk < 2; ++kk) {
      bf16x8 af[4], bv[2];
      for (int r = 0; r < 4; ++r) af[r] = *(const bf16x8*)(Ald + (aoff[r] ^ (kk << 5)));
      for (int c = 0; c < 2; ++c) bv[c] = *(const bf16x8*)(Bld + (boff[c] ^ (kk << 5)));
      for (int r = 0; r < 4; ++r)
        for (int c = 0; c < 2; ++c)
          acc[r][c] = __builtin_amdgcn_mfma_f32_16x16x32_bf16(af[r], bv[c], acc[r][c], 0, 0, 0);
    }
  }

  // -------- epilogue: stage through LDS, store 16B/lane (full 128B lines)
  __syncthreads();  // all LDS reads of K-loop done before smem reuse
  if (MODE != 2) {
    bf16_t* Ot = (bf16_t*)smem;  // [128][64]
    for (int r = 0; r < 4; ++r)
      for (int c = 0; c < 2; ++c) {
        int rowb = wr + r * 16 + quad * 4;
        int nl = wc + c * 16 + col;
        int n = n0 + nl;
        for (int i = 0; i < 4; ++i) {
          float av = acc[r][c][i];
          float vv;
          if (MODE == 0) {
            float bias = (n < 768) ? bqp[n] : (n < 1536) ? bkp[n - 768] : bvp[n - 1536];
            vv = av + bias;
          } else {
            float v = av + biasE[(size_t)e * biasStride + n];
            float u = v * (0.7978845608f + 0.0356774081f * v * v);
            float t2 = 1.f - 2.f / (1.f + __expf(2.f * u));
            vv = 0.5f * v * (1.f + t2);
          }
          Ot[(rowb + i) * 64 + nl] = (bf16_t)vv;
        }
      }
    __syncthreads();
    for (int q = 0; q < 4; ++q) {
      int rr = q * 32 + (tid >> 3);
      int cl = (tid & 7) * 8;
      int gm = m0 + rr;
      if (MODE == 0) {
        *(uint4*)(outB + (size_t)gm * N + n0 + cl) = *(const uint4*)(Ot + rr * 64 + cl);
      } else if (gm < cnt) {
        *(uint4*)(outB + (size_t)(off + gm) * N + n0 + cl) = *(const uint4*)(Ot + rr * 64 + cl);
      }
    }
  } else {
    float* Of = (float*)smem;  // [64][64] fp32, two half-tiles
    for (int p = 0; p < 2; ++p) {
      if ((w >> 1) == p) {
        for (int r = 0; r < 4; ++r)
          for (int c = 0; c < 2; ++c) {
            int rl = r * 16 + quad * 4;
            int nl = wc + c * 16 + col;
            for (int i = 0; i < 4; ++i) Of[(rl + i) * 64 + nl] = acc[r][c][i];
          }
      }
      __syncthreads();
      for (int q = 0; q < 4; ++q) {
        int rl = q * 16 + (tid >> 4);
        int gm = m0 + p * 64 + rl;
        if (gm < cnt) {
          int tok = perm[off + gm];
          *(float4*)(outF + (size_t)ks * Tc * Hc + (size_t)tok * N + n0 + (tid & 15) * 4) =
              *(const float4*)(Of + rl * 64 + (tid & 15) * 4);
        }
      }
      __syncthreads();
    }
  }
}

// ---------------------------------------------------------------- attention
__global__ __launch_bounds__(256) void attn_k(const bf16_t* __restrict__ qkv,
                                              const int* __restrict__ np,
                                              float* __restrict__ x) {
  __shared__ bf16_t Kld[256 * 64];  // reused as P after scores
  __shared__ bf16_t Vt[64 * 256];   // V transposed [d][s], swizzled
  int tid = threadIdx.x, lane = tid & 63, w = tid >> 6;
  int qt = blockIdx.x;
  int b = blockIdx.y / NHc, h = blockIdx.y % NHc;

  for (int j = 0; j < 8; ++j) {
    int rbase = w * 64 + j * 8;
    int row = rbase + (lane >> 3);
    int oc = ((lane & 7) - row) & 7;
    const bf16_t* gp = qkv + ((size_t)(b * 256 + row)) * 2304 + 768 + h * 64 + oc * 8;
    gll16(gp, Kld + rbase * 64);
  }
  {
    int s = tid, shi = s >> 3, slo = s & 7;
    const uint4* vs = (const uint4*)(qkv + ((size_t)(b * 256 + s)) * 2304 + 1536 + h * 64);
    for (int cc = 0; cc < 8; ++cc) {
      uint4 pk = vs[cc];
      const bf16_t* pv = (const bf16_t*)&pk;
      for (int jj = 0; jj < 8; ++jj) {
        int d = cc * 8 + jj;
        Vt[d * 256 + ((shi + d) & 31) * 8 + slo] = pv[jj];
      }
    }
  }
  int quad = lane >> 4, col = lane & 15;
  float madd[16];
  for (int nt = 0; nt < 16; ++nt)
    madd[nt] = (np[b * 256 + nt * 16 + col] != 0) ? 0.f : -10000.f;
  int qrow = qt * 64 + w * 16 + col;
  const bf16_t* qb = qkv + ((size_t)(b * 256 + qrow)) * 2304 + h * 64;
  bf16x8 qf0 = *(const bf16x8*)(qb + quad * 8);
  bf16x8 qf1 = *(const bf16x8*)(qb + 32 + quad * 8);
  __syncthreads();

  const f32x4 z4 = {0.f, 0.f, 0.f, 0.f};
  f32x4 sc[16];
  for (int nt = 0; nt < 16; ++nt) {
    int row = nt * 16 + col;
    bf16x8 k0 = *(const bf16x8*)(Kld + row * 64 + (((0 + quad + row) & 7) << 3));
    bf16x8 k1 = *(const bf16x8*)(Kld + row * 64 + (((4 + quad + row) & 7) << 3));
    f32x4 z = z4;
    z = __builtin_amdgcn_mfma_f32_16x16x32_bf16(qf0, k0, z, 0, 0, 0);
    z = __builtin_amdgcn_mfma_f32_16x16x32_bf16(qf1, k1, z, 0, 0, 0);
    sc[nt] = z;
  }
  for (int nt = 0; nt < 16; ++nt) {
    float a = madd[nt];
    sc[nt][0] += a; sc[nt][1] += a; sc[nt][2] += a; sc[nt][3] += a;
  }
  float pm[4], rl[4];
  for (int i = 0; i < 4; ++i) {
    float m = -1e30f;
    for (int nt = 0; nt < 16; ++nt) m = fmaxf(m, sc[nt][i]);
    for (int o = 1; o < 16; o <<= 1) m = fmaxf(m, __shfl_xor(m, o));
    float ssum = 0.f;
    for (int nt = 0; nt < 16; ++nt) ssum += __expf(sc[nt][i] - m);
    for (int o = 1; o < 16; o <<= 1) ssum += __shfl_xor(ssum, o);
    pm[i] = m;
    rl[i] = 1.f / ssum;
  }
  __syncthreads();
  bf16_t* Pb = Kld + w * 4096;
  for (int nt = 0; nt < 16; ++nt)
    for (int i = 0; i < 4; ++i) {
      int prow = quad * 4 + i;
      int key = nt * 16 + col;
      Pb[prow * 256 + (((key >> 3) + prow) & 31) * 8 + (key & 7)] =
          (bf16_t)__expf(sc[nt][i] - pm[i]);
    }
  __syncthreads();
  f32x4 oacc[4];
  for (int i = 0; i < 4; ++i) oacc[i] = z4;
  for (int kk2 = 0; kk2 < 8; ++kk2) {
    bf16x8 pa = *(const bf16x8*)(Pb + col * 256 + (((kk2 * 4 + quad + col) & 31) << 3));
    for (int nt2 = 0; nt2 < 4; ++nt2) {
      int d = nt2 * 16 + col;
      bf16x8 bv8 = *(const bf16x8*)(Vt + d * 256 + (((kk2 * 4 + quad + d) & 31) << 3));
      oacc[nt2] = __builtin_amdgcn_mfma_f32_16x16x32_bf16(pa, bv8, oacc[nt2], 0, 0, 0);
    }
  }
  for (int nt2 = 0; nt2 < 4; ++nt2)
    for (int i = 0; i < 4; ++i) {
      size_t o = ((size_t)(b * 256 + qt * 64 + w * 16 + quad * 4 + i)) * Hc + h * 64 + nt2 * 16 + col;
      x[o] += oacc[nt2][i] * rl[i];
    }
}

// ---------------------------------------------------------------- combine partials + residual + b2 + permute
__global__ __launch_bounds__(256) void combine_k(const float* __restrict__ x0,
                                                 const float* __restrict__ pbuf,
                                                 const float* __restrict__ b2l,
                                                 const int* __restrict__ ntp,
                                                 const int* __restrict__ np,
                                                 float* __restrict__ dst) {
  int i = blockIdx.x * 256 + threadIdx.x;  // float4 index over 2048*192
  int t = i / 192, d = i - t * 192;
  int idx = np[t];
  float4 o;
  if (idx != 0) {
    int r = idx - 1;
    int e = ntp[r];
    size_t j = (size_t)r * 192 + d;
    float4 a = ((const float4*)x0)[j];
    float4 p0 = ((const float4*)pbuf)[j];
    float4 p1 = ((const float4*)pbuf)[(size_t)Tc * 192 + j];
    float4 bb = ((const float4*)(b2l + (size_t)e * Hc))[d];
    o.x = a.x + p0.x + p1.x + bb.x;
    o.y = a.y + p0.y + p1.y + bb.y;
    o.z = a.z + p0.z + p1.z + bb.z;
    o.w = a.w + p0.w + p1.w + bb.w;
  } else {
    o.x = o.y = o.z = o.w = 0.f;
  }
  ((float4*)dst)[i] = o;
}

// ---------------------------------------------------------------- host
extern "C" void kernel_launch(void* const* d_in, const int* in_sizes, int n_in,
                              void* d_out, int out_size, void* d_ws, size_t ws_size,
                              hipStream_t stream) {
  const float* x_in = (const float*)d_in[0];
  const int* note_pos = (const int*)d_in[1];
  const int* ntp = (const int*)d_in[2];
  const float* Wq = (const float*)d_in[3];
  const float* bq = (const float*)d_in[4];
  const float* Wk = (const float*)d_in[5];
  const float* bk = (const float*)d_in[6];
  const float* Wv = (const float*)d_in[7];
  const float* bv = (const float*)d_in[8];
  const float* ln1w = (const float*)d_in[9];
  const float* ln1b = (const float*)d_in[10];
  const float* ln2w = (const float*)d_in[11];
  const float* ln2b = (const float*)d_in[12];
  const float* W1 = (const float*)d_in[13];
  const float* b1 = (const float*)d_in[14];
  const float* W2 = (const float*)d_in[15];
  const float* b2 = (const float*)d_in[16];
  float* out = (float*)d_out;

  char* p = (char*)d_ws;
  auto carve = [&](size_t bytes) -> char* {
    char* r = p;
    p += (bytes + 255) & ~(size_t)255;
    return r;
  };
  float* xA = (float*)carve((size_t)Tc * Hc * 4);
  float* xB = (float*)carve((size_t)Tc * Hc * 4);
  float* pbuf = (float*)carve((size_t)2 * Tc * Hc * 4);
  bf16_t* h16 = (bf16_t*)carve((size_t)Tc * Hc * 2);
  bf16_t* big = (bf16_t*)carve((size_t)Tc * FFc * 2);  // union: qkv16 / act1
  bf16_t* qkv16 = big;
  bf16_t* act1 = big;
  bf16_t* wqkvt = (bf16_t*)carve((size_t)Lc * 2304 * 768 * 2);
  bf16_t* w1t = (bf16_t*)carve((size_t)Lc * NEc * FFc * Hc * 2);
  bf16_t* w2t = (bf16_t*)carve((size_t)Lc * NEc * Hc * FFc * 2);
  int* perm = (int*)carve(Tc * 4);
  int* offs = (int*)carve(64);

  prep_k<<<1 + Tc * Hc / 2 / 256, 256, 0, stream>>>(x_in, ntp, xA, perm, offs);
  tconv_all<<<864 + 4608 + 4608, 256, 0, stream>>>(Wq, Wk, Wv, W1, W2, wqkvt, w1t, w2t);

  float* xcur = xA;
  for (int l = 0; l < Lc; ++l) {
    float* xdst = (l == Lc - 1) ? out : xB;
    ln_k<<<Tc / 4, 256, 0, stream>>>(xcur, ln1w + l * Hc, ln1b + l * Hc, h16);
    gemm4<0><<<dim3(36, 16, 1), 256, 0, stream>>>(
        h16, wqkvt + (size_t)l * 2304 * 768, Hc, 2304, 12, 0L, 0L, perm, offs,
        bq + l * Hc, bk + l * Hc, bv + l * Hc, nullptr, nullptr, qkv16);
    attn_k<<<dim3(4, Bc * NHc), 256, 0, stream>>>(qkv16, note_pos, xcur);
    ln_k<<<Tc / 4, 256, 0, stream>>>(xcur, ln2w + l * Hc, ln2b + l * Hc, h16);
    gemm4<1><<<dim3(48, 16, NEc), 256, 0, stream>>>(
        h16, w1t + (size_t)l * NEc * FFc * Hc, Hc, FFc, 12, (long)FFc * Hc, (long)FFc,
        perm, offs, nullptr, nullptr, nullptr, b1 + (size_t)l * NEc * FFc, nullptr, act1);
    gemm4<2><<<dim3(12, 16, NEc * 2), 256, 0, stream>>>(
        act1, w2t + (size_t)l * NEc * Hc * FFc, FFc, Hc, 24, (long)Hc * FFc, 0L,
        perm, offs, nullptr, nullptr, nullptr, nullptr, pbuf, nullptr);
    combine_k<<<Tc * 192 / 256, 256, 0, stream>>>(xcur, pbuf, b2 + (size_t)l * NEc * Hc,
                                                  ntp, note_pos, xdst);
    float* tmp = xcur; xcur = xdst; xB = tmp;  // ping-pong
  }
}

// Round 9
// 425.319 us; speedup vs baseline: 1.5608x; 1.0095x over previous
//
#include <hip/hip_runtime.h>

typedef __bf16 bf16_t;
typedef __attribute__((ext_vector_type(8))) __bf16 bf16x8;
typedef __attribute__((ext_vector_type(4))) float f32x4;

static constexpr int Lc = 2, NEc = 4, Hc = 768, FFc = 3072, NHc = 12;
static constexpr int Bc = 8, Tc = 2048;

__device__ __forceinline__ void gll16(const bf16_t* g, bf16_t* l) {
  __builtin_amdgcn_global_load_lds(
      (const __attribute__((address_space(1))) void*)g,
      (__attribute__((address_space(3))) void*)l, 16, 0, 0);
}

// ---------------------------------------------------------------- prep: block 0 = route (wave 0), blocks 1.. = PE add
__global__ __launch_bounds__(256) void prep_k(const float* __restrict__ xin,
                                              const int* __restrict__ ntp,
                                              float* __restrict__ x0,
                                              int* __restrict__ perm,
                                              int* __restrict__ offs) {
  if (blockIdx.x == 0) {
    int tid = threadIdx.x;
    if (tid >= 64) return;
    int lane = tid;
    int myE[32];
    int cnt0 = 0, cnt1 = 0, cnt2 = 0, cnt3 = 0;
    for (int c = 0; c < 32; ++c) {
      int e = ntp[c * 64 + lane];
      myE[c] = e;
      cnt0 += __popcll(__ballot(e == 0));
      cnt1 += __popcll(__ballot(e == 1));
      cnt2 += __popcll(__ballot(e == 2));
      cnt3 += __popcll(__ballot(e == 3));
    }
    int b0 = 0, b1 = cnt0, b2 = cnt0 + cnt1, b3 = cnt0 + cnt1 + cnt2;
    if (lane == 0) {
      offs[0] = 0; offs[1] = b1; offs[2] = b2; offs[3] = b3; offs[4] = b3 + cnt3;
    }
    unsigned long long below = (lane == 63) ? ~0ull >> 1 : ((1ull << lane) - 1);
    for (int c = 0; c < 32; ++c) {
      int e = myE[c];
      unsigned long long m0 = __ballot(e == 0), m1 = __ballot(e == 1);
      unsigned long long m2 = __ballot(e == 2), m3 = __ballot(e == 3);
      unsigned long long mm = (e == 0) ? m0 : (e == 1) ? m1 : (e == 2) ? m2 : m3;
      int base = (e == 0) ? b0 : (e == 1) ? b1 : (e == 2) ? b2 : b3;
      perm[base + __popcll(mm & below)] = c * 64 + lane;
      b0 += __popcll(m0); b1 += __popcll(m1); b2 += __popcll(m2); b3 += __popcll(m3);
    }
    return;
  }
  int p = (blockIdx.x - 1) * 256 + threadIdx.x;  // pair index over T*H/2
  int t = p / 384;
  int jj = p - t * 384;
  int s = t & 255;
  float ang = (float)s * __expf((float)jj * -0.0239852613894f);
  float sn, cs;
  sincosf(ang, &sn, &cs);
  float2 xv = ((const float2*)xin)[p];
  float2 o;  o.x = xv.x + sn;  o.y = xv.y + cs;
  ((float2*)x0)[p] = o;
}

// ---------------------------------------------------------------- LayerNorm
__global__ __launch_bounds__(256) void ln_k(const float* __restrict__ x,
                                            const float* __restrict__ g,
                                            const float* __restrict__ bb,
                                            bf16_t* __restrict__ out) {
  int w = threadIdx.x >> 6, lane = threadIdx.x & 63;
  int t = blockIdx.x * 4 + w;
  const float4* xr = (const float4*)(x + (size_t)t * Hc);
  float4 v[3];
  float s = 0.f, s2 = 0.f;
  for (int i = 0; i < 3; ++i) {
    v[i] = xr[lane + i * 64];
    s  += v[i].x + v[i].y + v[i].z + v[i].w;
    s2 += v[i].x * v[i].x + v[i].y * v[i].y + v[i].z * v[i].z + v[i].w * v[i].w;
  }
  for (int o = 1; o < 64; o <<= 1) { s += __shfl_xor(s, o); s2 += __shfl_xor(s2, o); }
  float mu = s * (1.f / 768.f);
  float r = rsqrtf(s2 * (1.f / 768.f) - mu * mu + 1e-5f);
  bf16_t* orow = out + (size_t)t * Hc;
  for (int i = 0; i < 3; ++i) {
    int i4 = lane + i * 64;
    float4 gg = ((const float4*)g)[i4];
    float4 b4 = ((const float4*)bb)[i4];
    union { bf16_t h[4]; uint2 u; } pk;
    pk.h[0] = (bf16_t)((v[i].x - mu) * r * gg.x + b4.x);
    pk.h[1] = (bf16_t)((v[i].y - mu) * r * gg.y + b4.y);
    pk.h[2] = (bf16_t)((v[i].z - mu) * r * gg.z + b4.z);
    pk.h[3] = (bf16_t)((v[i].w - mu) * r * gg.w + b4.w);
    ((uint2*)orow)[i4] = pk.u;
  }
}

// ---------------------------------------------------------------- unified transpose+convert fp32 [K,N] -> bf16 [N,K]
// 128x128 tiles: 512B read segments, 256B write segments (kills partial-line
// write RFO that made FETCH ~= WRITE at 64x64). bf16 staged in LDS [128][132].
// Grid: QKV (216) | W1 (1152) | W2 (1152).
__global__ __launch_bounds__(256) void tconv_all(const float* __restrict__ Wq,
                                                 const float* __restrict__ Wk,
                                                 const float* __restrict__ Wv,
                                                 const float* __restrict__ W1,
                                                 const float* __restrict__ W2,
                                                 bf16_t* __restrict__ wqkvt,
                                                 bf16_t* __restrict__ w1t,
                                                 bf16_t* __restrict__ w2t) {
  int t = blockIdx.x;
  const float* src;
  bf16_t* d;
  int K, N, n0, k0;
  if (t < 216) {
    int z = t / 36, r = t % 36;
    int l = z / 3, m = z % 3;
    src = (m == 0 ? Wq : (m == 1 ? Wk : Wv)) + (size_t)l * Hc * Hc;
    d = wqkvt + (size_t)l * 2304 * 768 + (size_t)m * Hc * Hc;
    K = 768; N = 768;
    n0 = (r % 6) * 128; k0 = (r / 6) * 128;
  } else if (t < 216 + 1152) {
    t -= 216;
    int z = t / 144, r = t % 144;
    src = W1 + (size_t)z * Hc * FFc;
    d = w1t + (size_t)z * FFc * Hc;
    K = 768; N = 3072;
    n0 = (r % 24) * 128; k0 = (r / 24) * 128;
  } else {
    t -= 216 + 1152;
    int z = t / 144, r = t % 144;
    src = W2 + (size_t)z * FFc * Hc;
    d = w2t + (size_t)z * Hc * FFc;
    K = 3072; N = 768;
    n0 = (r % 6) * 128; k0 = (r / 6) * 128;
  }
  __shared__ bf16_t tl[128][132];  // +4 bf16 pad per row
  // read side: 32 lanes/row (float4 each), 8 rows/pass, 16 passes; cvt to bf16 on ingest
  int cl = threadIdx.x & 31, rw = threadIdx.x >> 5;
  for (int i = 0; i < 16; ++i) {
    int r = rw + i * 8;
    float4 v = *(const float4*)(src + (size_t)(k0 + r) * N + n0 + cl * 4);
    union { bf16_t h[4]; uint2 u; } pk;
    pk.h[0] = (bf16_t)v.x; pk.h[1] = (bf16_t)v.y;
    pk.h[2] = (bf16_t)v.z; pk.h[3] = (bf16_t)v.w;
    *(uint2*)&tl[r][cl * 4] = pk.u;
  }
  __syncthreads();
  // write side: 16 lanes/row (uint4 = 8 bf16 each -> 256B/row), 16 rows/pass, 8 passes
  int c8 = threadIdx.x & 15, rr0 = threadIdx.x >> 4;
  for (int i = 0; i < 8; ++i) {
    int rr = rr0 + i * 16;
    union { bf16_t h[8]; uint4 u; } pk;
    for (int j = 0; j < 8; ++j) pk.h[j] = tl[c8 * 8 + j][rr];
    *(uint4*)(d + (size_t)(n0 + rr) * K + k0 + c8 * 8) = pk.u;
  }
}

// ---------------------------------------------------------------- GEMM, BM=128, BN=64, BK=64, 4 waves (2x2, each 64x32)
// LDS rows: 64 bf16 (8 chunks of 8), rotation swizzle: slot s of row r holds chunk (s-r)&7.
// Vectorized LDS-staged epilogue (full-line stores).
// MODE 0: QKV (bf16 out + range bias)  MODE 1: FFN1 (gather via perm, GELU, grouped out)
// MODE 2: FFN2 split-K=2 -> fp32 partial buffers (scatter by tok)
template <int MODE>
__global__ __launch_bounds__(256, 2) void gemm4(
    const bf16_t* __restrict__ A, const bf16_t* __restrict__ Bt,
    int K, int N, int kIters, long btStride, long biasStride,
    const int* __restrict__ perm, const int* __restrict__ offs,
    const float* __restrict__ bqp, const float* __restrict__ bkp,
    const float* __restrict__ bvp, const float* __restrict__ biasE,
    float* __restrict__ outF, bf16_t* __restrict__ outB) {
  __shared__ __align__(16) char smem[24576];
  bf16_t* Ald = (bf16_t*)smem;           // 128x64 = 16KB
  bf16_t* Bld = Ald + 128 * 64;          // 64x64  =  8KB
  int tid = threadIdx.x, lane = tid & 63, w = tid >> 6;
  int quad = lane >> 4, col = lane & 15;
  int m0 = blockIdx.y * 128, n0 = blockIdx.x * 64;
  int e = 0, ks = 0, kStart = 0, off = 0, cnt = Tc;
  if (MODE == 1) e = blockIdx.z;
  if (MODE == 2) { e = blockIdx.z >> 1; ks = blockIdx.z & 1; kStart = ks * (K / 2); }
  if (MODE != 0) {
    off = offs[e];
    cnt = offs[e + 1] - off;
    if (m0 >= cnt) return;
  }
  const bf16_t* B0 = Bt + (size_t)e * btStride;

  // A staging: wave w covers rows [w*32, w*32+32), 4 gll16 (8 rows each)
  const bf16_t* ga[4];
  bf16_t* la[4];
  for (int j = 0; j < 4; ++j) {
    int rbase = w * 32 + j * 8;
    int row = rbase + (lane >> 3);
    int ch = ((lane & 7) - row) & 7;
    int gm = m0 + row;
    int gmc = (gm < cnt) ? gm : (cnt - 1);
    int srow;
    if (MODE == 0) srow = gm;
    else if (MODE == 1) srow = perm[off + gmc];
    else srow = off + gmc;
    ga[j] = A + (size_t)srow * K + kStart + ch * 8;
    la[j] = Ald + rbase * 64;
  }
  // B staging: wave w covers rows [w*16, w*16+16), 2 gll16
  const bf16_t* gb[2];
  bf16_t* lb[2];
  for (int j = 0; j < 2; ++j) {
    int rbase = w * 16 + j * 8;
    int row = rbase + (lane >> 3);
    int ch = ((lane & 7) - row) & 7;
    gb[j] = B0 + (size_t)(n0 + row) * K + kStart + ch * 8;
    lb[j] = Bld + rbase * 64;
  }

  int wr = (w >> 1) * 64, wc = (w & 1) * 32;
  int aoff[4], boff[2];
  for (int r = 0; r < 4; ++r) {
    int row = wr + r * 16 + col;
    aoff[r] = row * 64 + (((quad + row) & 7) << 3);
  }
  for (int c = 0; c < 2; ++c) {
    int row = wc + c * 16 + col;
    boff[c] = row * 64 + (((quad + row) & 7) << 3);
  }

  const f32x4 z4 = {0.f, 0.f, 0.f, 0.f};
  f32x4 acc[4][2];
  for (int r = 0; r < 4; ++r)
    for (int c = 0; c < 2; ++c) acc[r][c] = z4;

  for (int it = 0; it < kIters; ++it) {
    __syncthreads();
    for (int j = 0; j < 4; ++j) { gll16(ga[j], la[j]); ga[j] += 64; }
    for (int j = 0; j < 2; ++j) { gll16(gb[j], lb[j]); gb[j] += 64; }
    __syncthreads();
    for (int kk = 0; kk < 2; ++kk) {
      bf16x8 af[4], bv[2];
      for (int r = 0; r < 4; ++r) af[r] = *(const bf16x8*)(Ald + (aoff[r] ^ (kk << 5)));
      for (int c = 0; c < 2; ++c) bv[c] = *(const bf16x8*)(Bld + (boff[c] ^ (kk << 5)));
      for (int r = 0; r < 4; ++r)
        for (int c = 0; c < 2; ++c)
          acc[r][c] = __builtin_amdgcn_mfma_f32_16x16x32_bf16(af[r], bv[c], acc[r][c], 0, 0, 0);
    }
  }

  // -------- epilogue: stage through LDS, store 16B/lane (full 128B lines)
  __syncthreads();  // all LDS reads of K-loop done before smem reuse
  if (MODE != 2) {
    bf16_t* Ot = (bf16_t*)smem;  // [128][64]
    for (int r = 0; r < 4; ++r)
      for (int c = 0; c < 2; ++c) {
        int rowb = wr + r * 16 + quad * 4;
        int nl = wc + c * 16 + col;
        int n = n0 + nl;
        for (int i = 0; i < 4; ++i) {
          float av = acc[r][c][i];
          float vv;
          if (MODE == 0) {
            float bias = (n < 768) ? bqp[n] : (n < 1536) ? bkp[n - 768] : bvp[n - 1536];
            vv = av + bias;
          } else {
            float v = av + biasE[(size_t)e * biasStride + n];
            float u = v * (0.7978845608f + 0.0356774081f * v * v);
            float t2 = 1.f - 2.f / (1.f + __expf(2.f * u));
            vv = 0.5f * v * (1.f + t2);
          }
          Ot[(rowb + i) * 64 + nl] = (bf16_t)vv;
        }
      }
    __syncthreads();
    for (int q = 0; q < 4; ++q) {
      int rr = q * 32 + (tid >> 3);
      int cl = (tid & 7) * 8;
      int gm = m0 + rr;
      if (MODE == 0) {
        *(uint4*)(outB + (size_t)gm * N + n0 + cl) = *(const uint4*)(Ot + rr * 64 + cl);
      } else if (gm < cnt) {
        *(uint4*)(outB + (size_t)(off + gm) * N + n0 + cl) = *(const uint4*)(Ot + rr * 64 + cl);
      }
    }
  } else {
    float* Of = (float*)smem;  // [64][64] fp32, two half-tiles
    for (int p = 0; p < 2; ++p) {
      if ((w >> 1) == p) {
        for (int r = 0; r < 4; ++r)
          for (int c = 0; c < 2; ++c) {
            int rl = r * 16 + quad * 4;
            int nl = wc + c * 16 + col;
            for (int i = 0; i < 4; ++i) Of[(rl + i) * 64 + nl] = acc[r][c][i];
          }
      }
      __syncthreads();
      for (int q = 0; q < 4; ++q) {
        int rl = q * 16 + (tid >> 4);
        int gm = m0 + p * 64 + rl;
        if (gm < cnt) {
          int tok = perm[off + gm];
          *(float4*)(outF + (size_t)ks * Tc * Hc + (size_t)tok * N + n0 + (tid & 15) * 4) =
              *(const float4*)(Of + rl * 64 + (tid & 15) * 4);
        }
      }
      __syncthreads();
    }
  }
}

// ---------------------------------------------------------------- attention
__global__ __launch_bounds__(256) void attn_k(const bf16_t* __restrict__ qkv,
                                              const int* __restrict__ np,
                                              float* __restrict__ x) {
  __shared__ bf16_t Kld[256 * 64];  // reused as P after scores
  __shared__ bf16_t Vt[64 * 256];   // V transposed [d][s], swizzled
  int tid = threadIdx.x, lane = tid & 63, w = tid >> 6;
  int qt = blockIdx.x;
  int b = blockIdx.y / NHc, h = blockIdx.y % NHc;

  for (int j = 0; j < 8; ++j) {
    int rbase = w * 64 + j * 8;
    int row = rbase + (lane >> 3);
    int oc = ((lane & 7) - row) & 7;
    const bf16_t* gp = qkv + ((size_t)(b * 256 + row)) * 2304 + 768 + h * 64 + oc * 8;
    gll16(gp, Kld + rbase * 64);
  }
  {
    int s = tid, shi = s >> 3, slo = s & 7;
    const uint4* vs = (const uint4*)(qkv + ((size_t)(b * 256 + s)) * 2304 + 1536 + h * 64);
    for (int cc = 0; cc < 8; ++cc) {
      uint4 pk = vs[cc];
      const bf16_t* pv = (const bf16_t*)&pk;
      for (int jj = 0; jj < 8; ++jj) {
        int d = cc * 8 + jj;
        Vt[d * 256 + ((shi + d) & 31) * 8 + slo] = pv[jj];
      }
    }
  }
  int quad = lane >> 4, col = lane & 15;
  float madd[16];
  for (int nt = 0; nt < 16; ++nt)
    madd[nt] = (np[b * 256 + nt * 16 + col] != 0) ? 0.f : -10000.f;
  int qrow = qt * 64 + w * 16 + col;
  const bf16_t* qb = qkv + ((size_t)(b * 256 + qrow)) * 2304 + h * 64;
  bf16x8 qf0 = *(const bf16x8*)(qb + quad * 8);
  bf16x8 qf1 = *(const bf16x8*)(qb + 32 + quad * 8);
  __syncthreads();

  const f32x4 z4 = {0.f, 0.f, 0.f, 0.f};
  f32x4 sc[16];
  for (int nt = 0; nt < 16; ++nt) {
    int row = nt * 16 + col;
    bf16x8 k0 = *(const bf16x8*)(Kld + row * 64 + (((0 + quad + row) & 7) << 3));
    bf16x8 k1 = *(const bf16x8*)(Kld + row * 64 + (((4 + quad + row) & 7) << 3));
    f32x4 z = z4;
    z = __builtin_amdgcn_mfma_f32_16x16x32_bf16(qf0, k0, z, 0, 0, 0);
    z = __builtin_amdgcn_mfma_f32_16x16x32_bf16(qf1, k1, z, 0, 0, 0);
    sc[nt] = z;
  }
  for (int nt = 0; nt < 16; ++nt) {
    float a = madd[nt];
    sc[nt][0] += a; sc[nt][1] += a; sc[nt][2] += a; sc[nt][3] += a;
  }
  float pm[4], rl[4];
  for (int i = 0; i < 4; ++i) {
    float m = -1e30f;
    for (int nt = 0; nt < 16; ++nt) m = fmaxf(m, sc[nt][i]);
    for (int o = 1; o < 16; o <<= 1) m = fmaxf(m, __shfl_xor(m, o));
    float ssum = 0.f;
    for (int nt = 0; nt < 16; ++nt) ssum += __expf(sc[nt][i] - m);
    for (int o = 1; o < 16; o <<= 1) ssum += __shfl_xor(ssum, o);
    pm[i] = m;
    rl[i] = 1.f / ssum;
  }
  __syncthreads();
  bf16_t* Pb = Kld + w * 4096;
  for (int nt = 0; nt < 16; ++nt)
    for (int i = 0; i < 4; ++i) {
      int prow = quad * 4 + i;
      int key = nt * 16 + col;
      Pb[prow * 256 + (((key >> 3) + prow) & 31) * 8 + (key & 7)] =
          (bf16_t)__expf(sc[nt][i] - pm[i]);
    }
  __syncthreads();
  f32x4 oacc[4];
  for (int i = 0; i < 4; ++i) oacc[i] = z4;
  for (int kk2 = 0; kk2 < 8; ++kk2) {
    bf16x8 pa = *(const bf16x8*)(Pb + col * 256 + (((kk2 * 4 + quad + col) & 31) << 3));
    for (int nt2 = 0; nt2 < 4; ++nt2) {
      int d = nt2 * 16 + col;
      bf16x8 bv8 = *(const bf16x8*)(Vt + d * 256 + (((kk2 * 4 + quad + d) & 31) << 3));
      oacc[nt2] = __builtin_amdgcn_mfma_f32_16x16x32_bf16(pa, bv8, oacc[nt2], 0, 0, 0);
    }
  }
  for (int nt2 = 0; nt2 < 4; ++nt2)
    for (int i = 0; i < 4; ++i) {
      size_t o = ((size_t)(b * 256 + qt * 64 + w * 16 + quad * 4 + i)) * Hc + h * 64 + nt2 * 16 + col;
      x[o] += oacc[nt2][i] * rl[i];
    }
}

// ---------------------------------------------------------------- combine partials + residual + b2 + permute
__global__ __launch_bounds__(256) void combine_k(const float* __restrict__ x0,
                                                 const float* __restrict__ pbuf,
                                                 const float* __restrict__ b2l,
                                                 const int* __restrict__ ntp,
                                                 const int* __restrict__ np,
                                                 float* __restrict__ dst) {
  int i = blockIdx.x * 256 + threadIdx.x;  // float4 index over 2048*192
  int t = i / 192, d = i - t * 192;
  int idx = np[t];
  float4 o;
  if (idx != 0) {
    int r = idx - 1;
    int e = ntp[r];
    size_t j = (size_t)r * 192 + d;
    float4 a = ((const float4*)x0)[j];
    float4 p0 = ((const float4*)pbuf)[j];
    float4 p1 = ((const float4*)pbuf)[(size_t)Tc * 192 + j];
    float4 bb = ((const float4*)(b2l + (size_t)e * Hc))[d];
    o.x = a.x + p0.x + p1.x + bb.x;
    o.y = a.y + p0.y + p1.y + bb.y;
    o.z = a.z + p0.z + p1.z + bb.z;
    o.w = a.w + p0.w + p1.w + bb.w;
  } else {
    o.x = o.y = o.z = o.w = 0.f;
  }
  ((float4*)dst)[i] = o;
}

// ---------------------------------------------------------------- host
extern "C" void kernel_launch(void* const* d_in, const int* in_sizes, int n_in,
                              void* d_out, int out_size, void* d_ws, size_t ws_size,
                              hipStream_t stream) {
  const float* x_in = (const float*)d_in[0];
  const int* note_pos = (const int*)d_in[1];
  const int* ntp = (const int*)d_in[2];
  const float* Wq = (const float*)d_in[3];
  const float* bq = (const float*)d_in[4];
  const float* Wk = (const float*)d_in[5];
  const float* bk = (const float*)d_in[6];
  const float* Wv = (const float*)d_in[7];
  const float* bv = (const float*)d_in[8];
  const float* ln1w = (const float*)d_in[9];
  const float* ln1b = (const float*)d_in[10];
  const float* ln2w = (const float*)d_in[11];
  const float* ln2b = (const float*)d_in[12];
  const float* W1 = (const float*)d_in[13];
  const float* b1 = (const float*)d_in[14];
  const float* W2 = (const float*)d_in[15];
  const float* b2 = (const float*)d_in[16];
  float* out = (float*)d_out;

  char* p = (char*)d_ws;
  auto carve = [&](size_t bytes) -> char* {
    char* r = p;
    p += (bytes + 255) & ~(size_t)255;
    return r;
  };
  float* xA = (float*)carve((size_t)Tc * Hc * 4);
  float* xB = (float*)carve((size_t)Tc * Hc * 4);
  float* pbuf = (float*)carve((size_t)2 * Tc * Hc * 4);
  bf16_t* h16 = (bf16_t*)carve((size_t)Tc * Hc * 2);
  bf16_t* big = (bf16_t*)carve((size_t)Tc * FFc * 2);  // union: qkv16 / act1
  bf16_t* qkv16 = big;
  bf16_t* act1 = big;
  bf16_t* wqkvt = (bf16_t*)carve((size_t)Lc * 2304 * 768 * 2);
  bf16_t* w1t = (bf16_t*)carve((size_t)Lc * NEc * FFc * Hc * 2);
  bf16_t* w2t = (bf16_t*)carve((size_t)Lc * NEc * Hc * FFc * 2);
  int* perm = (int*)carve(Tc * 4);
  int* offs = (int*)carve(64);

  prep_k<<<1 + Tc * Hc / 2 / 256, 256, 0, stream>>>(x_in, ntp, xA, perm, offs);
  tconv_all<<<216 + 1152 + 1152, 256, 0, stream>>>(Wq, Wk, Wv, W1, W2, wqkvt, w1t, w2t);

  float* xcur = xA;
  for (int l = 0; l < Lc; ++l) {
    float* xdst = (l == Lc - 1) ? out : xB;
    ln_k<<<Tc / 4, 256, 0, stream>>>(xcur, ln1w + l * Hc, ln1b + l * Hc, h16);
    gemm4<0><<<dim3(36, 16, 1), 256, 0, stream>>>(
        h16, wqkvt + (size_t)l * 2304 * 768, Hc, 2304, 12, 0L, 0L, perm, offs,
        bq + l * Hc, bk + l * Hc, bv + l * Hc, nullptr, nullptr, qkv16);
    attn_k<<<dim3(4, Bc * NHc), 256, 0, stream>>>(qkv16, note_pos, xcur);
    ln_k<<<Tc / 4, 256, 0, stream>>>(xcur, ln2w + l * Hc, ln2b + l * Hc, h16);
    gemm4<1><<<dim3(48, 16, NEc), 256, 0, stream>>>(
        h16, w1t + (size_t)l * NEc * FFc * Hc, Hc, FFc, 12, (long)FFc * Hc, (long)FFc,
        perm, offs, nullptr, nullptr, nullptr, b1 + (size_t)l * NEc * FFc, nullptr, act1);
    gemm4<2><<<dim3(12, 16, NEc * 2), 256, 0, stream>>>(
        act1, w2t + (size_t)l * NEc * Hc * FFc, FFc, Hc, 24, (long)Hc * FFc, 0L,
        perm, offs, nullptr, nullptr, nullptr, nullptr, pbuf, nullptr);
    combine_k<<<Tc * 192 / 256, 256, 0, stream>>>(xcur, pbuf, b2 + (size_t)l * NEc * Hc,
                                                  ntp, note_pos, xdst);
    float* tmp = xcur; xcur = xdst; xB = tmp;  // ping-pong
  }
}